// Round 1
// baseline (259.794 us; speedup 1.0000x reference)
//
#include <hip/hip_runtime.h>
#include <hip/hip_bf16.h>

#define NROWS 8192
#define DIM   256

typedef __attribute__((ext_vector_type(8))) short short8;
typedef __attribute__((ext_vector_type(4))) float f32x4;

// ---------------------------------------------------------------------------
// Kernel 1: L2-normalize each row of latent (fp32) and store as bf16.
// One 256-thread block per row.
// ---------------------------------------------------------------------------
__global__ void normalize_kernel(const float* __restrict__ latent,
                                 __hip_bfloat16* __restrict__ zbf) {
    int row = blockIdx.x;
    int tid = threadIdx.x;                 // 0..255
    float x = latent[row * DIM + tid];
    float s = x * x;
    #pragma unroll
    for (int m = 32; m; m >>= 1) s += __shfl_xor(s, m, 64);
    __shared__ float wsum[4];
    if ((tid & 63) == 0) wsum[tid >> 6] = s;
    __syncthreads();
    float tot = wsum[0] + wsum[1] + wsum[2] + wsum[3];
    float scale = rsqrtf(tot);
    zbf[row * DIM + tid] = __float2bfloat16(x * scale);
}

// ---------------------------------------------------------------------------
// Kernel 2: fused sim = (z z^T)/T with per-row masked reductions.
// Block: 512 threads = 8 waves. Block owns 16 rows (A frags in registers for
// the whole K=256). Each wave sweeps 1024 columns in 16-col tiles.
// Per-lane accumulators -> 16-lane butterfly -> LDS combine -> atomicAdd.
// ---------------------------------------------------------------------------
__global__ __launch_bounds__(512, 4)
void ntxent_main(const __hip_bfloat16* __restrict__ zbf16,
                 const int* __restrict__ labels,
                 float* __restrict__ acc_out) {
    const unsigned short* zb = (const unsigned short*)zbf16;
    const int tid  = threadIdx.x;
    const int wave = tid >> 6;
    const int lane = tid & 63;
    const int lrow = lane & 15;   // A-row / B-col within tile
    const int kgrp = lane >> 4;   // 0..3
    const int rowBase = blockIdx.x * 16;

    // --- A fragments for this block's 16 rows, full K=256, in registers ---
    short8 a[8];
    {
        const short8* aptr =
            (const short8*)(zb + (rowBase + lrow) * DIM + kgrp * 8);
        #pragma unroll
        for (int kk = 0; kk < 8; ++kk) a[kk] = aptr[kk * 4];  // +32 shorts/step
    }

    const int grow0 = rowBase + kgrp * 4;     // global rows this lane owns
    int labr[4];
    #pragma unroll
    for (int j = 0; j < 4; ++j) labr[j] = labels[grow0 + j];

    float se[4] = {0.f, 0.f, 0.f, 0.f};   // sum exp(sim) over non-self
    float ps[4] = {0.f, 0.f, 0.f, 0.f};   // sum cos over positives
    float np[4] = {0.f, 0.f, 0.f, 0.f};   // count positives

    const int colStart = wave * (NROWS / 8);  // 1024 cols per wave

    for (int t = 0; t < (NROWS / 8) / 16; ++t) {   // 64 tiles
        const int colBase = colStart + t * 16;
        const int gcol = colBase + lrow;
        const short8* bptr = (const short8*)(zb + gcol * DIM + kgrp * 8);

        f32x4 c0 = {0.f, 0.f, 0.f, 0.f};
        f32x4 c1 = {0.f, 0.f, 0.f, 0.f};
        #pragma unroll
        for (int kk = 0; kk < 8; kk += 2) {
            c0 = __builtin_amdgcn_mfma_f32_16x16x32_bf16(a[kk],     bptr[kk * 4],       c0, 0, 0, 0);
            c1 = __builtin_amdgcn_mfma_f32_16x16x32_bf16(a[kk + 1], bptr[(kk + 1) * 4], c1, 0, 0, 0);
        }
        const f32x4 c = c0 + c1;   // cos(z_row, z_col)

        const int labc = labels[gcol];
        #pragma unroll
        for (int j = 0; j < 4; ++j) {
            const float tv  = c[j];
            const bool slf  = (gcol == grow0 + j);
            const float e   = __expf(tv * 10.0f);   // exp(sim), sim = cos/T
            const bool pos  = (labc == labr[j]) && !slf;
            se[j] += slf ? 0.0f : e;
            ps[j] += pos ? tv   : 0.0f;
            np[j] += pos ? 1.0f : 0.0f;
        }
    }

    // --- reduce across the 16 lanes of each kgrp group (same rows) ---
    #pragma unroll
    for (int j = 0; j < 4; ++j) {
        #pragma unroll
        for (int m = 1; m < 16; m <<= 1) {
            se[j] += __shfl_xor(se[j], m, 64);
            ps[j] += __shfl_xor(ps[j], m, 64);
            np[j] += __shfl_xor(np[j], m, 64);
        }
    }

    __shared__ float pse[8][16], pps[8][16], pnp[8][16];
    if (lrow == 0) {
        #pragma unroll
        for (int j = 0; j < 4; ++j) {
            pse[wave][kgrp * 4 + j] = se[j];
            pps[wave][kgrp * 4 + j] = ps[j];
            pnp[wave][kgrp * 4 + j] = np[j];
        }
    }
    __syncthreads();

    if (tid < 16) {
        float S = 0.f, P = 0.f, N = 0.f;
        #pragma unroll
        for (int w = 0; w < 8; ++w) {
            S += pse[w][tid]; P += pps[w][tid]; N += pnp[w][tid];
        }
        const float lse  = __logf(S);
        const float mean = 10.0f * P / fmaxf(N, 1.0f);
        float contrib = (N > 0.0f) ? (lse - mean) : 0.0f;  // -(mean_pos - lse)
        float hp      = (N > 0.0f) ? 1.0f : 0.0f;
        #pragma unroll
        for (int m = 1; m < 16; m <<= 1) {
            contrib += __shfl_xor(contrib, m, 64);
            hp      += __shfl_xor(hp, m, 64);
        }
        if (tid == 0) {
            atomicAdd(&acc_out[0], contrib);
            atomicAdd(&acc_out[1], hp);
        }
    }
}

// ---------------------------------------------------------------------------
// Kernel 3: finalize scalar
// ---------------------------------------------------------------------------
__global__ void finalize_kernel(const float* __restrict__ acc,
                                float* __restrict__ out) {
    out[0] = acc[0] / fmaxf(acc[1], 1.0f);
}

extern "C" void kernel_launch(void* const* d_in, const int* in_sizes, int n_in,
                              void* d_out, int out_size, void* d_ws, size_t ws_size,
                              hipStream_t stream) {
    const float* latent = (const float*)d_in[0];
    const int*   labels = (const int*)d_in[1];
    float* out = (float*)d_out;

    __hip_bfloat16* zbf = (__hip_bfloat16*)d_ws;
    float* acc = (float*)((char*)d_ws + (size_t)NROWS * DIM * sizeof(__hip_bfloat16));

    hipMemsetAsync(acc, 0, 2 * sizeof(float), stream);
    normalize_kernel<<<NROWS, DIM, 0, stream>>>(latent, zbf);
    ntxent_main<<<NROWS / 16, 512, 0, stream>>>(zbf, labels, acc);
    finalize_kernel<<<1, 1, 0, stream>>>(acc, out);
}

// Round 2
// 158.219 us; speedup vs baseline: 1.6420x; 1.6420x over previous
//
#include <hip/hip_runtime.h>
#include <hip/hip_bf16.h>

#define NROWS 8192
#define DIM   256
#define BM    32                              // rows per block (A in registers)
#define CS    4                               // column splits
#define COLS_PER_BLOCK (NROWS / CS)           // 2048
#define COLS_PER_WAVE  (COLS_PER_BLOCK / 8)   // 256
#define NT             (COLS_PER_WAVE / 16)   // 16 tiles per wave

typedef __attribute__((ext_vector_type(8))) short short8;
typedef __attribute__((ext_vector_type(4))) float f32x4;

// ---------------------------------------------------------------------------
// Kernel 1: L2-normalize each row of latent (fp32) and store as bf16.
// ---------------------------------------------------------------------------
__global__ void normalize_kernel(const float* __restrict__ latent,
                                 __hip_bfloat16* __restrict__ zbf) {
    int row = blockIdx.x;
    int tid = threadIdx.x;                 // 0..255
    float x = latent[row * DIM + tid];
    float s = x * x;
    #pragma unroll
    for (int m = 32; m; m >>= 1) s += __shfl_xor(s, m, 64);
    __shared__ float wsum[4];
    if ((tid & 63) == 0) wsum[tid >> 6] = s;
    __syncthreads();
    float tot = wsum[0] + wsum[1] + wsum[2] + wsum[3];
    float scale = rsqrtf(tot);
    zbf[row * DIM + tid] = __float2bfloat16(x * scale);
}

// ---------------------------------------------------------------------------
// Kernel 2: fused sim reductions. Block = 512 threads = 8 waves; block owns
// 32 rows (A frags in registers, 64 VGPRs); each wave sweeps 256 columns
// (16 tiles) of a 2048-column slice. B tiles double-buffered in registers
// (explicit prefetch). Per-row partials (sum exp excl self, sum cos over
// label-matches INCLUDING self) atomically accumulated to workspace.
// ---------------------------------------------------------------------------
__global__ __launch_bounds__(512, 2)
void ntxent_main(const __hip_bfloat16* __restrict__ zbf16,
                 const int* __restrict__ labels,
                 float* __restrict__ se_sum,
                 float* __restrict__ ps_sum) {
    const unsigned short* zb = (const unsigned short*)zbf16;
    const int tid  = threadIdx.x;
    const int wave = tid >> 6;
    const int lane = tid & 63;
    const int lrow = lane & 15;   // A-row / B-col within 16x16 tile
    const int kgrp = lane >> 4;   // 0..3
    const int rb = blockIdx.x / CS;
    const int cb = blockIdx.x % CS;
    const int rowBase = rb * BM;

    // --- A fragments: 32 rows, full K=256, in registers ---
    short8 a0[8], a1[8];
    {
        const short8* p0 = (const short8*)(zb + (rowBase + lrow) * DIM + kgrp * 8);
        const short8* p1 = (const short8*)(zb + (rowBase + 16 + lrow) * DIM + kgrp * 8);
        #pragma unroll
        for (int kk = 0; kk < 8; ++kk) { a0[kk] = p0[kk * 4]; a1[kk] = p1[kk * 4]; }
    }

    const int grow0 = rowBase + kgrp * 4;        // rows held in c0 frags
    const int grow1 = grow0 + 16;                // rows held in c1 frags
    int labr[8];
    #pragma unroll
    for (int j = 0; j < 4; ++j) {
        labr[j]     = labels[grow0 + j];
        labr[4 + j] = labels[grow1 + j];
    }

    float se[8] = {0.f}, ps[8] = {0.f};

    const int colStart = cb * COLS_PER_BLOCK + wave * COLS_PER_WAVE;

    auto loadB = [&](short8* b, int colTile) {
        const short8* bp = (const short8*)(zb + (colTile + lrow) * DIM + kgrp * 8);
        #pragma unroll
        for (int kk = 0; kk < 8; ++kk) b[kk] = bp[kk * 4];
    };

    auto computeT = [&](const short8* b, int colTile) {
        f32x4 c00 = {0.f,0.f,0.f,0.f}, c01 = {0.f,0.f,0.f,0.f};
        f32x4 c10 = {0.f,0.f,0.f,0.f}, c11 = {0.f,0.f,0.f,0.f};
        #pragma unroll
        for (int kk = 0; kk < 8; kk += 2) {
            c00 = __builtin_amdgcn_mfma_f32_16x16x32_bf16(a0[kk],     b[kk],     c00, 0, 0, 0);
            c10 = __builtin_amdgcn_mfma_f32_16x16x32_bf16(a1[kk],     b[kk],     c10, 0, 0, 0);
            c01 = __builtin_amdgcn_mfma_f32_16x16x32_bf16(a0[kk + 1], b[kk + 1], c01, 0, 0, 0);
            c11 = __builtin_amdgcn_mfma_f32_16x16x32_bf16(a1[kk + 1], b[kk + 1], c11, 0, 0, 0);
        }
        const f32x4 c0 = c00 + c01;   // rows grow0..grow0+3, col = colTile+lrow
        const f32x4 c1 = c10 + c11;   // rows grow1..grow1+3
        const int gcol = colTile + lrow;
        const int labc = labels[gcol];
        #pragma unroll
        for (int j = 0; j < 4; ++j) {
            {
                const float tv = c0[j];
                const float e  = __expf(tv * 10.0f);
                se[j] += (gcol == grow0 + j) ? 0.0f : e;
                ps[j] += (labc == labr[j])   ? tv   : 0.0f;   // includes self; fixed in final
            }
            {
                const float tv = c1[j];
                const float e  = __expf(tv * 10.0f);
                se[4 + j] += (gcol == grow1 + j)   ? 0.0f : e;
                ps[4 + j] += (labc == labr[4 + j]) ? tv   : 0.0f;
            }
        }
    };

    // --- software-pipelined sweep: prefetch B tile t+1 while computing t ---
    short8 bA[8], bB[8];
    loadB(bA, colStart);
    #pragma unroll 1
    for (int t = 0; t < NT; t += 2) {
        loadB(bB, colStart + (t + 1) * 16);
        computeT(bA, colStart + t * 16);
        if (t + 2 < NT) loadB(bA, colStart + (t + 2) * 16);
        computeT(bB, colStart + (t + 1) * 16);
    }

    // --- reduce across the 16 lanes (cols) of each kgrp group ---
    #pragma unroll
    for (int j = 0; j < 8; ++j) {
        #pragma unroll
        for (int m = 1; m < 16; m <<= 1) {
            se[j] += __shfl_xor(se[j], m, 64);
            ps[j] += __shfl_xor(ps[j], m, 64);
        }
    }

    __shared__ float pse[8][BM], pps[8][BM];
    if (lrow == 0) {
        #pragma unroll
        for (int j = 0; j < 4; ++j) {
            pse[wave][kgrp * 4 + j]      = se[j];
            pse[wave][16 + kgrp * 4 + j] = se[4 + j];
            pps[wave][kgrp * 4 + j]      = ps[j];
            pps[wave][16 + kgrp * 4 + j] = ps[4 + j];
        }
    }
    __syncthreads();

    if (tid < BM) {
        float S = 0.f, P = 0.f;
        #pragma unroll
        for (int w = 0; w < 8; ++w) { S += pse[w][tid]; P += pps[w][tid]; }
        atomicAdd(&se_sum[rowBase + tid], S);
        atomicAdd(&ps_sum[rowBase + tid], P);
    }
}

// ---------------------------------------------------------------------------
// Kernel 3: label histogram -> per-row loss -> scalar. One 1024-thread block.
// n_pos[i] = hist[label[i]] - 1 (self excluded). ps included self (cos~1),
// subtract 1.0 analytically.
// ---------------------------------------------------------------------------
__global__ __launch_bounds__(1024)
void ntxent_final(const float* __restrict__ se_sum,
                  const float* __restrict__ ps_sum,
                  const int* __restrict__ labels,
                  float* __restrict__ out) {
    __shared__ int hist[128];
    __shared__ float redc[16], redh[16];
    const int tid = threadIdx.x;
    if (tid < 128) hist[tid] = 0;
    __syncthreads();
    for (int i = tid; i < NROWS; i += 1024) atomicAdd(&hist[labels[i]], 1);
    __syncthreads();

    float contrib = 0.f, hp = 0.f;
    for (int i = tid; i < NROWS; i += 1024) {
        const int n = hist[labels[i]] - 1;
        if (n > 0) {
            const float lse  = __logf(se_sum[i]);
            const float mean = 10.0f * (ps_sum[i] - 1.0f) / (float)n;
            contrib += lse - mean;
            hp += 1.0f;
        }
    }
    #pragma unroll
    for (int m = 32; m; m >>= 1) {
        contrib += __shfl_xor(contrib, m, 64);
        hp      += __shfl_xor(hp, m, 64);
    }
    if ((tid & 63) == 0) { redc[tid >> 6] = contrib; redh[tid >> 6] = hp; }
    __syncthreads();
    if (tid == 0) {
        float c = 0.f, h = 0.f;
        #pragma unroll
        for (int w = 0; w < 16; ++w) { c += redc[w]; h += redh[w]; }
        out[0] = c / fmaxf(h, 1.0f);
    }
}

extern "C" void kernel_launch(void* const* d_in, const int* in_sizes, int n_in,
                              void* d_out, int out_size, void* d_ws, size_t ws_size,
                              hipStream_t stream) {
    const float* latent = (const float*)d_in[0];
    const int*   labels = (const int*)d_in[1];
    float* out = (float*)d_out;

    __hip_bfloat16* zbf = (__hip_bfloat16*)d_ws;
    float* se_sum = (float*)((char*)d_ws + (size_t)NROWS * DIM * sizeof(__hip_bfloat16));
    float* ps_sum = se_sum + NROWS;

    hipMemsetAsync(se_sum, 0, 2 * NROWS * sizeof(float), stream);
    normalize_kernel<<<NROWS, DIM, 0, stream>>>(latent, zbf);
    ntxent_main<<<(NROWS / BM) * CS, 512, 0, stream>>>(zbf, labels, se_sum, ps_sum);
    ntxent_final<<<1, 1024, 0, stream>>>(se_sum, ps_sum, labels, out);
}

// Round 3
// 88.597 us; speedup vs baseline: 2.9323x; 1.7858x over previous
//
#include <hip/hip_runtime.h>
#include <hip/hip_bf16.h>

#define NROWS 8192
#define DIM   256
#define BM    128                         // rows per block = 4 waves x 32
#define CS    32                          // column splits (multiple of 8 for XCD locality)
#define COLS_PER_BLOCK (NROWS / CS)       // 256
#define NTILES (COLS_PER_BLOCK / 16)      // 16
#define NBUF  4
#define TILE_BYTES (16 * DIM * 2)         // 8 KB per 16-col tile

typedef __attribute__((ext_vector_type(8))) short short8;
typedef __attribute__((ext_vector_type(4))) float f32x4;

__device__ __forceinline__ unsigned short f2bf(float x) {
    __hip_bfloat16 h = __float2bfloat16(x);
    unsigned short u;
    __builtin_memcpy(&u, &h, sizeof(u));
    return u;
}

// ---------------------------------------------------------------------------
// Kernel 1: L2-normalize rows, fp32 -> bf16. 4 rows/block, float4 loads.
// ---------------------------------------------------------------------------
__global__ __launch_bounds__(256)
void normalize_kernel(const float* __restrict__ latent,
                      unsigned short* __restrict__ zb) {
    const int wave = threadIdx.x >> 6, lane = threadIdx.x & 63;
    const int row = blockIdx.x * 4 + wave;
    const float4 v = ((const float4*)(latent + (size_t)row * DIM))[lane];
    float s = v.x * v.x + v.y * v.y + v.z * v.z + v.w * v.w;
    #pragma unroll
    for (int m = 32; m; m >>= 1) s += __shfl_xor(s, m, 64);
    const float sc = rsqrtf(s);
    ushort4 o;
    o.x = f2bf(v.x * sc); o.y = f2bf(v.y * sc);
    o.z = f2bf(v.z * sc); o.w = f2bf(v.w * sc);
    ((ushort4*)(zb + (size_t)row * DIM))[lane] = o;
}

// ---------------------------------------------------------------------------
// Kernel 2: fused sim reductions with LDS-staged shared B tiles.
// 256 threads = 4 waves; wave w owns rows [rowBase+32w, rowBase+32w+32),
// A fragments in registers. B: 16-col tiles staged via global_load_lds into a
// 4-buffer LDS ring, counted-vmcnt pipeline (3 tiles in flight).
// ---------------------------------------------------------------------------
__global__ __launch_bounds__(256, 3)
void ntxent_main(const unsigned short* __restrict__ zb,
                 const int* __restrict__ labels,
                 float* __restrict__ se_sum,
                 float* __restrict__ ps_sum) {
    __shared__ __align__(16) char ldsB[NBUF * TILE_BYTES];   // 32 KB
    __shared__ int ldsLab[COLS_PER_BLOCK];                   // 1 KB

    const int tid  = threadIdx.x;
    const int wave = tid >> 6, lane = tid & 63;
    const int lrow = lane & 15, kgrp = lane >> 4;
    const int rb = blockIdx.x / CS, cb = blockIdx.x % CS;    // bid%8==cb%8 -> XCD locality
    const int rowBase  = rb * BM;
    const int colStart = cb * COLS_PER_BLOCK;
    const int rowW = rowBase + wave * 32;

    // --- prologue global loads (all VMEM issued BEFORE stages; drained at tile 0) ---
    const int mylab = labels[colStart + tid];                // this block's col labels
    const int grow0 = rowW + kgrp * 4;
    int labr[8];
    #pragma unroll
    for (int j = 0; j < 4; ++j) {
        labr[j]     = labels[grow0 + j];
        labr[4 + j] = labels[grow0 + 16 + j];
    }
    short8 a0[8], a1[8];
    {
        const short8* p0 = (const short8*)(zb + (size_t)(rowW + lrow) * DIM + kgrp * 8);
        const short8* p1 = (const short8*)(zb + (size_t)(rowW + 16 + lrow) * DIM + kgrp * 8);
        #pragma unroll
        for (int kk = 0; kk < 8; ++kk) { a0[kk] = p0[kk * 4]; a1[kk] = p1[kk * 4]; }
    }
    ldsLab[tid] = mylab;
    asm volatile("s_waitcnt lgkmcnt(0)" ::: "memory");

    // --- stage: 8 KB tile, 2 x global_load_lds_dwordx4 per thread.
    // LDS linear [c(0..15)][512B]; source pre-swizzled: byte o of col c comes
    // from global byte (o ^ ((c&7)<<4)) so ds_read applies the same XOR.
    auto stage = [&](int tt) {
        const int buf = tt & (NBUF - 1);
        const int colBase = colStart + tt * 16;
        #pragma unroll
        for (int h = 0; h < 2; ++h) {
            const int Lbase = h * 4096 + wave * 1024;        // wave-uniform LDS base
            const int L = Lbase + lane * 16;                 // this lane's slot
            const int c = L >> 9;
            const int o = L & 511;
            const int osw = o ^ ((c & 7) << 4);
            const unsigned short* src = zb + (size_t)(colBase + c) * DIM + (osw >> 1);
            __builtin_amdgcn_global_load_lds(
                (const __attribute__((address_space(1))) void*)src,
                (__attribute__((address_space(3))) void*)(ldsB + buf * TILE_BYTES + Lbase),
                16, 0, 0);
        }
    };

    float se[8] = {0.f, 0.f, 0.f, 0.f, 0.f, 0.f, 0.f, 0.f};
    float ps[8] = {0.f, 0.f, 0.f, 0.f, 0.f, 0.f, 0.f, 0.f};

    auto computeTile = [&](int t) {
        const int buf = t & (NBUF - 1);
        const int colBase = colStart + t * 16;
        const char* base = ldsB + buf * TILE_BYTES + lrow * 512;
        const int swz = (lrow & 7) << 4;

        f32x4 cA0 = {0.f,0.f,0.f,0.f}, cA1 = {0.f,0.f,0.f,0.f};
        f32x4 cB0 = {0.f,0.f,0.f,0.f}, cB1 = {0.f,0.f,0.f,0.f};
        #pragma unroll
        for (int kk = 0; kk < 8; kk += 2) {
            const short8 b0 = *(const short8*)(base + ((kgrp * 16 + kk * 64) ^ swz));
            const short8 b1 = *(const short8*)(base + ((kgrp * 16 + (kk + 1) * 64) ^ swz));
            cA0 = __builtin_amdgcn_mfma_f32_16x16x32_bf16(a0[kk],     b0, cA0, 0, 0, 0);
            cB0 = __builtin_amdgcn_mfma_f32_16x16x32_bf16(a1[kk],     b0, cB0, 0, 0, 0);
            cA1 = __builtin_amdgcn_mfma_f32_16x16x32_bf16(a0[kk + 1], b1, cA1, 0, 0, 0);
            cB1 = __builtin_amdgcn_mfma_f32_16x16x32_bf16(a1[kk + 1], b1, cB1, 0, 0, 0);
        }
        const f32x4 c0 = cA0 + cA1;   // rows grow0..+3,   col = colBase+lrow
        const f32x4 c1 = cB0 + cB1;   // rows grow0+16..+19
        const int gcol = colBase + lrow;
        const int labc = ldsLab[t * 16 + lrow];
        const bool diagT = (colBase < rowW + 32) && (rowW < colBase + 16);
        #pragma unroll
        for (int j = 0; j < 4; ++j) {
            const float tv0 = c0[j], tv1 = c1[j];
            float e0 = exp2f(tv0 * 14.4269504089f);   // exp(10*cos)
            float e1 = exp2f(tv1 * 14.4269504089f);
            if (diagT) {
                if (gcol == grow0 + j)      e0 = 0.f;
                if (gcol == grow0 + 16 + j) e1 = 0.f;
            }
            se[j]     += e0;
            se[4 + j] += e1;
            ps[j]     += (labc == labr[j])     ? tv0 : 0.f;  // includes self; fixed in final
            ps[4 + j] += (labc == labr[4 + j]) ? tv1 : 0.f;
        }
    };

    // --- counted-vmcnt pipeline: 4-buffer ring, 3 tiles in flight ---
    stage(0); stage(1); stage(2); stage(3);

    #pragma unroll 1
    for (int t = 0; t < NTILES - 4; ++t) {
        asm volatile("s_waitcnt vmcnt(6)" ::: "memory");   // tile t landed (own loads)
        __builtin_amdgcn_s_barrier();                      // all threads' loads landed
        asm volatile("" ::: "memory");
        computeTile(t);
        asm volatile("s_waitcnt lgkmcnt(0)" ::: "memory"); // ds_reads of buf t%4 retired
        __builtin_amdgcn_s_barrier();                      // safe to overwrite buf t%4
        stage(t + 4);
    }
    // tail: no more stages; drain 6 -> 4 -> 2 -> 0
    asm volatile("s_waitcnt vmcnt(6)" ::: "memory");
    __builtin_amdgcn_s_barrier();
    asm volatile("" ::: "memory");
    computeTile(NTILES - 4);
    asm volatile("s_waitcnt vmcnt(4)" ::: "memory");
    __builtin_amdgcn_s_barrier();
    asm volatile("" ::: "memory");
    computeTile(NTILES - 3);
    asm volatile("s_waitcnt vmcnt(2)" ::: "memory");
    __builtin_amdgcn_s_barrier();
    asm volatile("" ::: "memory");
    computeTile(NTILES - 2);
    asm volatile("s_waitcnt vmcnt(0)" ::: "memory");
    __builtin_amdgcn_s_barrier();
    asm volatile("" ::: "memory");
    computeTile(NTILES - 1);

    // --- per-row reduce over the 16 col-lanes; rows are wave-exclusive ---
    #pragma unroll
    for (int j = 0; j < 8; ++j) {
        #pragma unroll
        for (int m = 1; m < 16; m <<= 1) {
            se[j] += __shfl_xor(se[j], m, 64);
            ps[j] += __shfl_xor(ps[j], m, 64);
        }
    }
    if (lrow == 0) {
        #pragma unroll
        for (int j = 0; j < 4; ++j) {
            atomicAdd(&se_sum[grow0 + j],      se[j]);
            atomicAdd(&ps_sum[grow0 + j],      ps[j]);
            atomicAdd(&se_sum[grow0 + 16 + j], se[4 + j]);
            atomicAdd(&ps_sum[grow0 + 16 + j], ps[4 + j]);
        }
    }
}

// ---------------------------------------------------------------------------
// Kernel 3: label histogram -> per-row loss -> scalar.
// ps included self (cos ~ 1.0): subtract 1.0; n_pos = hist[label]-1.
// ---------------------------------------------------------------------------
__global__ __launch_bounds__(1024)
void ntxent_final(const float* __restrict__ se_sum,
                  const float* __restrict__ ps_sum,
                  const int* __restrict__ labels,
                  float* __restrict__ out) {
    __shared__ int hist[128];
    __shared__ float redc[16], redh[16];
    const int tid = threadIdx.x;
    if (tid < 128) hist[tid] = 0;
    __syncthreads();
    for (int i = tid; i < NROWS; i += 1024) atomicAdd(&hist[labels[i]], 1);
    __syncthreads();

    float contrib = 0.f, hp = 0.f;
    for (int i = tid; i < NROWS; i += 1024) {
        const int n = hist[labels[i]] - 1;
        if (n > 0) {
            const float lse  = __logf(se_sum[i]);
            const float mean = 10.0f * (ps_sum[i] - 1.0f) / (float)n;
            contrib += lse - mean;
            hp += 1.0f;
        }
    }
    #pragma unroll
    for (int m = 32; m; m >>= 1) {
        contrib += __shfl_xor(contrib, m, 64);
        hp      += __shfl_xor(hp, m, 64);
    }
    if ((tid & 63) == 0) { redc[tid >> 6] = contrib; redh[tid >> 6] = hp; }
    __syncthreads();
    if (tid == 0) {
        float c = 0.f, h = 0.f;
        #pragma unroll
        for (int w = 0; w < 16; ++w) { c += redc[w]; h += redh[w]; }
        out[0] = c / fmaxf(h, 1.0f);
    }
}

extern "C" void kernel_launch(void* const* d_in, const int* in_sizes, int n_in,
                              void* d_out, int out_size, void* d_ws, size_t ws_size,
                              hipStream_t stream) {
    const float* latent = (const float*)d_in[0];
    const int*   labels = (const int*)d_in[1];
    float* out = (float*)d_out;

    unsigned short* zb = (unsigned short*)d_ws;
    float* se_sum = (float*)((char*)d_ws + (size_t)NROWS * DIM * sizeof(unsigned short));
    float* ps_sum = se_sum + NROWS;

    hipMemsetAsync(se_sum, 0, 2 * NROWS * sizeof(float), stream);
    normalize_kernel<<<NROWS / 4, 256, 0, stream>>>(latent, zb);
    ntxent_main<<<(NROWS / BM) * CS, 256, 0, stream>>>(zb, labels, se_sum, ps_sum);
    ntxent_final<<<1, 1024, 0, stream>>>(se_sum, ps_sum, labels, out);
}